// Round 4
// baseline (12739.127 us; speedup 1.0000x reference)
//
#include <hip/hip_runtime.h>

#define B_ 64
#define S_ 512
#define D_ 1024
#define H_ 1024
#define NBLK 256
#define NT 256

typedef __bf16 v8bf __attribute__((ext_vector_type(8)));
typedef float v4f __attribute__((ext_vector_type(4)));
typedef float f32x4 __attribute__((ext_vector_type(4)));

// Persistent LSTM kernel. Inputs f32, OUTPUT f32 (reference is all-f32 JAX).
// Grid: 256 blocks x 256 threads. Block nb owns output columns [nb*4, nb*4+4)
// across all 4 gates (16 n-values). Weights for those 16 rows of [Wx;Wh]
// (16 x 2048, cvt f32->bf16 = 64KB) staged in LDS once, XOR-swizzled in 16B
// chunks so B-fragment ds_read_b128 is 2-way-bank-aliased (free on gfx950).
// Per step: g = [x_t, h_t] @ W^T via mfma_f32_16x16x32_bf16 (M=64 split
// across 4 waves, N=16, K=2048). h double-buffered (bf16) in ws; c in regs.
//
// ROUND 3 (latency restructure; resubmitted round 4 after infra-failed bench).
// Rounds 0-2 changed the barrier PROTOCOL (counter->flags->no-fences) for a
// combined -12%: the stall is protocol-invariant, i.e. serialized memory-
// latency chains inside the step:
//  (a) h-part: 128 sc1 dword loads/lane interleaved with dependent MFMAs ->
//      ~12 serialized MALL round trips (~800cy each). FIX: prefetch each
//      64-dword half into registers with zero deps, then consume (2 exposures).
//  (b) x-part: 64 float4 loads chained into MFMAs. FIX: ring prefetch depth 8.
//  (c) poll storm: 1024 waves spin-loading flags from MALL queue ahead of the
//      producer stores they await. FIX: only wave 0 polls (4 flags/lane);
//      waves 1-3 park at s_barrier.
__global__ __launch_bounds__(NT, 1)
void lstm_persist(const float* __restrict__ x,    // (B,S,D) f32
                  const float* __restrict__ Wx,   // (4,H,D) f32
                  const float* __restrict__ Wh,   // (4,H,H) f32
                  const float* __restrict__ bias, // (4,H)   f32
                  float* __restrict__ out,        // (B,S,H) ++ (B,H) ++ (B,H), f32
                  __bf16* __restrict__ hbuf,      // (2,B,H) bf16 double buffer
                  unsigned* __restrict__ flags)   // [NBLK] per-block step flags
{
  __shared__ v8bf wlds[16 * 256];  // [nl][kc ^ (nl&7)] 16B chunks, 64KB

  const int tid  = threadIdx.x;
  const int nb   = blockIdx.x;
  const int w    = tid >> 6;   // wave 0..3
  const int l    = tid & 63;
  const int lm   = l & 15;     // MFMA row (A) / col (B,D) lane index
  const int quad = l >> 4;     // MFMA k-quad
  const int sw   = lm & 7;     // LDS swizzle key

  // ---- stage weights into LDS (once), f32 -> bf16 ----
  for (int i = tid; i < 16 * 256; i += NT) {
    const int nl  = i >> 8;          // 0..15: gate g = nl>>2, local col = nl&3
    const int kc  = i & 255;         // 8-elt chunk index along K (k = kc*8)
    const int g   = nl >> 2;
    const int col = (nb << 2) + (nl & 3);
    const int k   = kc << 3;
    const float* src = (k < D_)
        ? (Wx + ((size_t)(g * H_ + col) * D_ + k))
        : (Wh + ((size_t)(g * H_ + col) * H_ + (k - D_)));
    f32x4 a = *(const f32x4*)src;
    f32x4 b = *(const f32x4*)(src + 4);
    v8bf r;
    r[0] = (__bf16)a[0]; r[1] = (__bf16)a[1]; r[2] = (__bf16)a[2]; r[3] = (__bf16)a[3];
    r[4] = (__bf16)b[0]; r[5] = (__bf16)b[1]; r[6] = (__bf16)b[2]; r[7] = (__bf16)b[3];
    wlds[(nl << 8) + (kc ^ (nl & 7))] = r;
  }

  const int myb   = (w << 4) + lm;      // batch row this lane owns
  const int mycol = (nb << 2) + quad;   // H-column this lane owns (elementwise)
  float bv[4];
  #pragma unroll
  for (int g = 0; g < 4; ++g) bv[g] = bias[g * H_ + mycol];

  float c_reg = 0.f;  // cell state for (myb, mycol), lives in a register

  __syncthreads();

  for (int t = 0; t < S_; ++t) {
    v4f acc[2];
    acc[0] = (v4f){0.f, 0.f, 0.f, 0.f};
    acc[1] = (v4f){0.f, 0.f, 0.f, 0.f};

    // ---- x part (K = 0..1023): ring-prefetched depth 8, no h dependence ----
    const float* xrow = x + ((size_t)(myb * S_ + t)) * D_ + (quad << 3);
    f32x4 xr[8][2];
    #pragma unroll
    for (int i = 0; i < 8; ++i) {
      xr[i][0] = *(const f32x4*)(xrow + (i << 5));
      xr[i][1] = *(const f32x4*)(xrow + (i << 5) + 4);
    }
    #pragma unroll
    for (int c = 0; c < 32; ++c) {
      const f32x4 u = xr[c & 7][0];
      const f32x4 v = xr[c & 7][1];
      if (c < 24) {  // refill ring slot for chunk c+8 (issues early)
        xr[c & 7][0] = *(const f32x4*)(xrow + ((c + 8) << 5));
        xr[c & 7][1] = *(const f32x4*)(xrow + ((c + 8) << 5) + 4);
      }
      v8bf a;
      a[0] = (__bf16)u[0]; a[1] = (__bf16)u[1]; a[2] = (__bf16)u[2]; a[3] = (__bf16)u[3];
      a[4] = (__bf16)v[0]; a[5] = (__bf16)v[1]; a[6] = (__bf16)v[2]; a[7] = (__bf16)v[3];
      v8bf b = wlds[(lm << 8) + (((c << 2) + quad) ^ sw)];
      acc[c & 1] = __builtin_amdgcn_mfma_f32_16x16x32_bf16(a, b, acc[c & 1], 0, 0, 0);
    }

    // ---- wait for all h_t writes, then h part (K = 1024..2047) ----
    if (t > 0) {
      if (w == 0) {  // only wave 0 polls: lane i watches flags[4i..4i+3]
        const unsigned tu = (unsigned)t;
        for (;;) {
          const unsigned f0 = __hip_atomic_load(&flags[(l << 2) + 0],
              __ATOMIC_RELAXED, __HIP_MEMORY_SCOPE_AGENT);
          const unsigned f1 = __hip_atomic_load(&flags[(l << 2) + 1],
              __ATOMIC_RELAXED, __HIP_MEMORY_SCOPE_AGENT);
          const unsigned f2 = __hip_atomic_load(&flags[(l << 2) + 2],
              __ATOMIC_RELAXED, __HIP_MEMORY_SCOPE_AGENT);
          const unsigned f3 = __hip_atomic_load(&flags[(l << 2) + 3],
              __ATOMIC_RELAXED, __HIP_MEMORY_SCOPE_AGENT);
          if ((f0 >= tu) & (f1 >= tu) & (f2 >= tu) & (f3 >= tu)) break;
          __builtin_amdgcn_s_sleep(1);
        }
      }
      __syncthreads();  // releases waves 1-3; orders h loads after the polls

      // h fragments: agent-scope (sc1, LLC-direct) dword loads. Two halves;
      // within a half all 64 loads are issued dep-free, then consumed.
      const unsigned* hrow =
          (const unsigned*)(hbuf + ((t & 1) ? (size_t)(B_ * H_) : 0)
                            + (size_t)myb * H_) + (quad << 2);
      #pragma unroll
      for (int half = 0; half < 2; ++half) {
        unsigned hreg[64];
        #pragma unroll
        for (int i = 0; i < 64; ++i) {
          const int c = (half << 4) + (i >> 2);  // K-chunk 0..31
          const int j = i & 3;
          hreg[i] = __hip_atomic_load(hrow + (c << 4) + j,
              __ATOMIC_RELAXED, __HIP_MEMORY_SCOPE_AGENT);
        }
        #pragma unroll
        for (int k = 0; k < 16; ++k) {
          const int c = (half << 4) + k;
          union { unsigned u[4]; v8bf v; } au;
          au.u[0] = hreg[(k << 2) + 0];
          au.u[1] = hreg[(k << 2) + 1];
          au.u[2] = hreg[(k << 2) + 2];
          au.u[3] = hreg[(k << 2) + 3];
          v8bf b = wlds[(lm << 8) + ((128 + (c << 2) + quad) ^ sw)];
          acc[c & 1] = __builtin_amdgcn_mfma_f32_16x16x32_bf16(au.v, b, acc[c & 1], 0, 0, 0);
        }
      }
    }

    v4f accs = acc[0] + acc[1];

    // ---- gate exchange: D layout row m=quad*4+r (batch), col n=lm.
    // Dest lane (b=16w+lm, c=quad) needs cols {g*4+quad} at row lm. ----
    float gv[4];
    const int rsel = lm & 3;
    #pragma unroll
    for (int g = 0; g < 4; ++g) {
      const int srcl = ((lm >> 2) << 4) + (g << 2) + quad;
      float t0 = __shfl(accs[0], srcl, 64);
      float t1 = __shfl(accs[1], srcl, 64);
      float t2 = __shfl(accs[2], srcl, 64);
      float t3 = __shfl(accs[3], srcl, 64);
      gv[g] = (rsel == 0 ? t0 : rsel == 1 ? t1 : rsel == 2 ? t2 : t3) + bv[g];
    }

    // ---- LSTM pointwise (fp32) ----
    const float it = 1.f / (1.f + __expf(-gv[0]));
    const float ft = 1.f / (1.f + __expf(-gv[1]));
    const float ot = 1.f / (1.f + __expf(-gv[2]));
    const float ch = 1.f - 2.f / (__expf(2.f * gv[3]) + 1.f);  // tanh
    c_reg = ft * c_reg + it * ch;
    const float hn = ot * (1.f - 2.f / (__expf(2.f * c_reg) + 1.f));

    // bf16 feedback: agent-scope (sc1) write-through store -> LLC. This is
    // what the flag release protects; __syncthreads' implicit vmcnt(0) drain
    // orders it before the flag store. No bulk fences anywhere.
    {
      union { __bf16 b; unsigned short s; } hb;
      hb.b = (__bf16)hn;
      __hip_atomic_store(
          (unsigned short*)(hbuf + (((t + 1) & 1) ? (size_t)(B_ * H_) : 0)
                            + (size_t)myb * H_ + mycol),
          hb.s, __ATOMIC_RELAXED, __HIP_MEMORY_SCOPE_AGENT);
    }

    __syncthreads();  // implicit s_waitcnt vmcnt(0): all h stores are at LLC
    if (tid == 0) {
      __hip_atomic_store(&flags[nb], (unsigned)(t + 1), __ATOMIC_RELAXED,
                         __HIP_MEMORY_SCOPE_AGENT);
    }

    // ---- streamed outputs: never re-read; nontemporal + after the release
    // so they stay off the critical path. ----
    __builtin_nontemporal_store(hn, &out[((size_t)(myb * S_ + t)) * H_ + mycol]);
    if (t == S_ - 1) {
      __builtin_nontemporal_store(
          hn, &out[(size_t)B_ * S_ * H_ + (size_t)myb * H_ + mycol]);   // h_last
      __builtin_nontemporal_store(
          c_reg, &out[(size_t)B_ * S_ * H_ + (size_t)(B_ * H_)
                      + (size_t)myb * H_ + mycol]);                      // c_last
    }
  }
}

extern "C" void kernel_launch(void* const* d_in, const int* in_sizes, int n_in,
                              void* d_out, int out_size, void* d_ws, size_t ws_size,
                              hipStream_t stream) {
  const float* x    = (const float*)d_in[0];
  const float* Wx   = (const float*)d_in[1];
  const float* Wh   = (const float*)d_in[2];
  const float* bias = (const float*)d_in[3];
  float* out = (float*)d_out;

  unsigned* flags = (unsigned*)d_ws;                 // NBLK*4 = 1KB region
  __bf16*   hbuf  = (__bf16*)((char*)d_ws + 4096);   // 2*B*H bf16 = 256KB

  // ws is poisoned 0xAA before every timed launch: zero the flag region.
  hipMemsetAsync(d_ws, 0, 4096, stream);

  lstm_persist<<<dim3(NBLK), dim3(NT), 0, stream>>>(x, Wx, Wh, bias, out, hbuf,
                                                    flags);
}

// Round 5
// 7102.413 us; speedup vs baseline: 1.7936x; 1.7936x over previous
//
#include <hip/hip_runtime.h>

#define B_ 64
#define S_ 512
#define D_ 1024
#define H_ 1024
#define NBLK 256
#define NT 256
#define TB 8   // out-store batch (steps buffered in registers)

typedef __bf16 v8bf __attribute__((ext_vector_type(8)));
typedef float v4f __attribute__((ext_vector_type(4)));
typedef float f32x4 __attribute__((ext_vector_type(4)));
typedef unsigned long long u64;

// Convert 8 consecutive f32 (32B, two float4 loads) to a bf16x8 fragment.
__device__ inline v8bf cvt8(const float* p) {
  f32x4 a = *(const f32x4*)p;
  f32x4 b = *(const f32x4*)(p + 4);
  v8bf r;
  r[0] = (__bf16)a[0]; r[1] = (__bf16)a[1]; r[2] = (__bf16)a[2]; r[3] = (__bf16)a[3];
  r[4] = (__bf16)b[0]; r[5] = (__bf16)b[1]; r[6] = (__bf16)b[2]; r[7] = (__bf16)b[3];
  return r;
}

// Persistent LSTM. Grid 256x256. Block nb owns output cols [nb*4,nb*4+4) x 4
// gates; weights for those 16 rows of [Wx;Wh] in LDS (64KB, XOR-swizzled).
// Per step: g = [x_t,h_t] @ W^T via mfma_f32_16x16x32_bf16, x-part before the
// wait, h double-buffered in ws, c in registers.
//
// ROUND 5 (barrier-free decoupled wave-systems + line-coalesced exchange).
// Rounds 0-4 falsified: barrier protocol, bulk fences, and load-latency
// prefetch all ~neutral (fixed ~24us/step, all pipes <4%). Untouched until
// now: (H1) every exchange store was sub-line scattered (hbuf: 16x8B runs per
// wave; out: 16x16B NT runs) and both per-step __syncthreads compiler-drain
// vmcnt(0), putting partial-line store acks on the critical path; (H4) the
// intra-block s_barrier coupling itself. Key structural fact: batch ownership
// = wave index, so consumer wave w only reads h produced by producer waves w
// -> the 4 waves form 4 fully decoupled 256-agent systems. This round:
//  1. ZERO s_barriers in the loop: per-wave flags flags[w][nb] (1024), each
//     wave drains only its own stores (inline s_waitcnt vmcnt(0)) and polls
//     only its own 256-flag slice. Quarter-systems pipeline independently.
//  2. Blocked h layout hblk[buf][nb][b*4+q]: producer wave writes 128B
//     contiguous (2 full lines) instead of 16 scattered 8B runs; consumer
//     gathers 8B chunks that coalesce into 128B runs per quad-group.
//  3. Out stores batched TB=8 steps in registers, flushed AFTER the flag
//     store -> NT scatters get ~8 steps of slack, never sit in a drain.
__global__ __launch_bounds__(NT, 1)
void lstm_persist(const float* __restrict__ x,    // (B,S,D) f32
                  const float* __restrict__ Wx,   // (4,H,D) f32
                  const float* __restrict__ Wh,   // (4,H,H) f32
                  const float* __restrict__ bias, // (4,H)   f32
                  float* __restrict__ out,        // (B,S,H) ++ (B,H) ++ (B,H), f32
                  __bf16* __restrict__ hblk,      // (2,NBLK,256) bf16 blocked h
                  unsigned* __restrict__ flags)   // [4][NBLK] per-wave step flags
{
  __shared__ v8bf wlds[16 * 256];  // [nl][kc ^ (nl&7)] 16B chunks, 64KB

  const int tid  = threadIdx.x;
  const int nb   = blockIdx.x;
  const int w    = tid >> 6;   // wave 0..3  (= wave-system id)
  const int l    = tid & 63;
  const int lm   = l & 15;     // MFMA row (A) / col (B,D) lane index
  const int quad = l >> 4;     // MFMA k-quad
  const int sw   = lm & 7;     // LDS swizzle key

  // ---- stage weights into LDS (once), f32 -> bf16 ----
  for (int i = tid; i < 16 * 256; i += NT) {
    const int nl  = i >> 8;          // 0..15: gate g = nl>>2, local col = nl&3
    const int kc  = i & 255;         // 8-elt chunk index along K (k = kc*8)
    const int g   = nl >> 2;
    const int col = (nb << 2) + (nl & 3);
    const int k   = kc << 3;
    const float* src = (k < D_)
        ? (Wx + ((size_t)(g * H_ + col) * D_ + k))
        : (Wh + ((size_t)(g * H_ + col) * H_ + (k - D_)));
    wlds[(nl << 8) + (kc ^ (nl & 7))] = cvt8(src);
  }

  const int myb   = (w << 4) + lm;      // batch row this lane owns
  const int myb4  = myb << 2;           // entry offset inside a producer tile
  const int mycol = (nb << 2) + quad;   // H-column this lane owns (elementwise)
  float bv[4];
  #pragma unroll
  for (int g = 0; g < 4; ++g) bv[g] = bias[g * H_ + mycol];

  float c_reg = 0.f;   // cell state for (myb, mycol)
  float obuf[TB];      // batched out values

  const unsigned* fw     = flags + (w << 8);       // my wave-system's 256 flags
  unsigned*       myflag = flags + (w << 8) + nb;  // my arrival flag

  __syncthreads();  // weights staged (only barrier in the kernel)

  for (int t = 0; t < S_; ++t) {
    v4f acc[2];
    acc[0] = (v4f){0.f, 0.f, 0.f, 0.f};
    acc[1] = (v4f){0.f, 0.f, 0.f, 0.f};

    // ---- x part (K = 0..1023): no dependence on h, runs before the wait ----
    const float* xrow = x + ((size_t)(myb * S_ + t)) * D_ + (quad << 3);
    #pragma unroll 4
    for (int qq = 0; qq < 16; ++qq) {
      const int q0 = qq * 2, q1 = qq * 2 + 1;
      v8bf a0 = cvt8(xrow + (q0 << 5));
      v8bf b0 = wlds[(lm << 8) + (((q0 << 2) + quad) ^ sw)];
      acc[0] = __builtin_amdgcn_mfma_f32_16x16x32_bf16(a0, b0, acc[0], 0, 0, 0);
      v8bf a1 = cvt8(xrow + (q1 << 5));
      v8bf b1 = wlds[(lm << 8) + (((q1 << 2) + quad) ^ sw)];
      acc[1] = __builtin_amdgcn_mfma_f32_16x16x32_bf16(a1, b1, acc[1], 0, 0, 0);
    }

    // ---- wait for wave-system w's 256 producers, then h part ----
    if (t > 0) {
      const unsigned tu = (unsigned)t;
      for (;;) {  // lane l watches fw[4l..4l+4): contiguous 1KB across wave
        const unsigned f0 = __hip_atomic_load(fw + (l << 2) + 0,
            __ATOMIC_RELAXED, __HIP_MEMORY_SCOPE_AGENT);
        const unsigned f1 = __hip_atomic_load(fw + (l << 2) + 1,
            __ATOMIC_RELAXED, __HIP_MEMORY_SCOPE_AGENT);
        const unsigned f2 = __hip_atomic_load(fw + (l << 2) + 2,
            __ATOMIC_RELAXED, __HIP_MEMORY_SCOPE_AGENT);
        const unsigned f3 = __hip_atomic_load(fw + (l << 2) + 3,
            __ATOMIC_RELAXED, __HIP_MEMORY_SCOPE_AGENT);
        if (__all((f0 >= tu) & (f1 >= tu) & (f2 >= tu) & (f3 >= tu))) break;
        __builtin_amdgcn_s_sleep(1);
      }
      asm volatile("" ::: "memory");  // no hoisting h loads above the poll

      // h fragment for chunk c (k = quad*8 + c*32): producer tiles j0,j0+1,
      // 8B each at hblk[buf][j][myb*4]. Agent-scope (sc1, LLC-direct) loads.
      const __bf16* hb = hblk + ((t & 1) ? (1 << 16) : 0);
      #pragma unroll 4
      for (int c = 0; c < 32; ++c) {
        const int j0 = (quad << 1) + (c << 3);
        union { u64 q[2]; v8bf v; } a;
        a.q[0] = __hip_atomic_load((const u64*)(hb + (j0 << 8) + myb4),
            __ATOMIC_RELAXED, __HIP_MEMORY_SCOPE_AGENT);
        a.q[1] = __hip_atomic_load((const u64*)(hb + ((j0 + 1) << 8) + myb4),
            __ATOMIC_RELAXED, __HIP_MEMORY_SCOPE_AGENT);
        v8bf b = wlds[(lm << 8) + ((128 + (c << 2) + quad) ^ sw)];
        acc[c & 1] = __builtin_amdgcn_mfma_f32_16x16x32_bf16(a.v, b, acc[c & 1], 0, 0, 0);
      }
    }

    v4f accs = acc[0] + acc[1];

    // ---- gate exchange: D layout row m=quad*4+r (batch), col n=lm.
    // Dest lane (b=16w+lm, c=quad) needs cols {g*4+quad} at row lm. ----
    float gv[4];
    const int rsel = lm & 3;
    #pragma unroll
    for (int g = 0; g < 4; ++g) {
      const int srcl = ((lm >> 2) << 4) + (g << 2) + quad;
      float t0 = __shfl(accs[0], srcl, 64);
      float t1 = __shfl(accs[1], srcl, 64);
      float t2 = __shfl(accs[2], srcl, 64);
      float t3 = __shfl(accs[3], srcl, 64);
      gv[g] = (rsel == 0 ? t0 : rsel == 1 ? t1 : rsel == 2 ? t2 : t3) + bv[g];
    }

    // ---- LSTM pointwise (fp32) ----
    const float it = 1.f / (1.f + __expf(-gv[0]));
    const float ft = 1.f / (1.f + __expf(-gv[1]));
    const float ot = 1.f / (1.f + __expf(-gv[2]));
    const float ch = 1.f - 2.f / (__expf(2.f * gv[3]) + 1.f);  // tanh
    c_reg = ft * c_reg + it * ch;
    const float hn = ot * (1.f - 2.f / (__expf(2.f * c_reg) + 1.f));

    // ---- blocked h store: wave writes 128B contiguous (2 full lines) ----
    {
      union { __bf16 b; unsigned short s; } hb2;
      hb2.b = (__bf16)hn;
      __hip_atomic_store(
          (unsigned short*)(hblk + (((t + 1) & 1) ? (1 << 16) : 0)
                            + (nb << 8) + myb4 + quad),
          hb2.s, __ATOMIC_RELAXED, __HIP_MEMORY_SCOPE_AGENT);
    }

    // ---- per-wave release: drain MY stores only, then arrive ----
    asm volatile("s_waitcnt vmcnt(0)" ::: "memory");
    __hip_atomic_store(myflag, (unsigned)(t + 1), __ATOMIC_RELAXED,
                       __HIP_MEMORY_SCOPE_AGENT);

    // ---- batched out stores (after the release; ~TB steps to drain) ----
    obuf[t & (TB - 1)] = hn;
    if ((t & (TB - 1)) == TB - 1) {
      #pragma unroll
      for (int i = 0; i < TB; ++i)
        __builtin_nontemporal_store(
            obuf[i], &out[((size_t)(myb * S_ + (t - TB + 1 + i))) * H_ + mycol]);
    }
    if (t == S_ - 1) {
      __builtin_nontemporal_store(
          hn, &out[(size_t)B_ * S_ * H_ + (size_t)myb * H_ + mycol]);   // h_last
      __builtin_nontemporal_store(
          c_reg, &out[(size_t)B_ * S_ * H_ + (size_t)(B_ * H_)
                      + (size_t)myb * H_ + mycol]);                      // c_last
    }
  }
}

extern "C" void kernel_launch(void* const* d_in, const int* in_sizes, int n_in,
                              void* d_out, int out_size, void* d_ws, size_t ws_size,
                              hipStream_t stream) {
  const float* x    = (const float*)d_in[0];
  const float* Wx   = (const float*)d_in[1];
  const float* Wh   = (const float*)d_in[2];
  const float* bias = (const float*)d_in[3];
  float* out = (float*)d_out;

  unsigned* flags = (unsigned*)d_ws;                 // 4*NBLK*4B = 4KB region
  __bf16*   hblk  = (__bf16*)((char*)d_ws + 4096);   // 2*256*256 bf16 = 256KB

  // ws is poisoned 0xAA before every timed launch: zero the flag region.
  hipMemsetAsync(d_ws, 0, 4096, stream);

  lstm_persist<<<dim3(NBLK), dim3(NT), 0, stream>>>(x, Wx, Wh, bias, out, hblk,
                                                    flags);
}